// Round 10
// baseline (204.691 us; speedup 1.0000x reference)
//
#include <hip/hip_runtime.h>
#include <hip/hip_fp16.h>

#define NN 100000
#define NB 391        // ceil(NN/256) buckets of 256 dst nodes
#define NG 256        // edge-pass blocks
#define SCAN_B 256

using f16x8 = __attribute__((ext_vector_type(8))) _Float16;
using f32x4 = __attribute__((ext_vector_type(4))) float;

// ---------------- pass A: per-block bucket histogram (LDS) ----------------
__global__ __launch_bounds__(256) void bhist_kernel(const int* __restrict__ dst,
                                                    int* __restrict__ counts, int E) {
    __shared__ int h[NB];
    for (int i = threadIdx.x; i < NB; i += 256) h[i] = 0;
    __syncthreads();
    const int chunk = (E + NG - 1) / NG;
    const int lo = blockIdx.x * chunk, hi = min(E, lo + chunk);
    for (int e = lo + threadIdx.x; e < hi; e += 256) atomicAdd(&h[dst[e] >> 8], 1);
    __syncthreads();
    for (int i = threadIdx.x; i < NB; i += 256) counts[i * NG + blockIdx.x] = h[i];
}

// ---------------- in-place exclusive scan over counts[M] ----------------
__global__ void scan1_kernel(int* __restrict__ a, int* __restrict__ blk_sums, int M) {
    __shared__ int sm[SCAN_B];
    int t = threadIdx.x, i = blockIdx.x * SCAN_B + t;
    int v = (i < M) ? a[i] : 0;
    sm[t] = v; __syncthreads();
    for (int off = 1; off < SCAN_B; off <<= 1) {
        int x = (t >= off) ? sm[t - off] : 0; __syncthreads();
        sm[t] += x; __syncthreads();
    }
    if (i < M) a[i] = sm[t] - v;
    if (t == SCAN_B - 1) blk_sums[blockIdx.x] = sm[t];
}

__global__ void scan2_kernel(const int* __restrict__ blk_sums, int* __restrict__ blk_off, int nblk) {
    __shared__ int sm[SCAN_B];
    __shared__ int run;
    int t = threadIdx.x;
    if (t == 0) run = 0;
    __syncthreads();
    for (int base = 0; base < nblk; base += SCAN_B) {
        int i = base + t;
        int v = (i < nblk) ? blk_sums[i] : 0;
        sm[t] = v; __syncthreads();
        for (int off = 1; off < SCAN_B; off <<= 1) {
            int x = (t >= off) ? sm[t - off] : 0; __syncthreads();
            sm[t] += x; __syncthreads();
        }
        if (i < nblk) blk_off[i] = run + sm[t] - v;
        __syncthreads();
        if (t == 0) run += sm[SCAN_B - 1];
        __syncthreads();
    }
}

__global__ void scan3_kernel(int* __restrict__ a, const int* __restrict__ blk_off, int M) {
    int i = blockIdx.x * SCAN_B + threadIdx.x;
    if (i < M) a[i] += blk_off[blockIdx.x];
}

// ---------------- pass C: scatter edges into bucket-contiguous staging ----------------
__global__ __launch_bounds__(256) void bscatter_kernel(const int* __restrict__ src,
                                                       const int* __restrict__ dst,
                                                       const int* __restrict__ cstart,
                                                       int* __restrict__ staging, int E) {
    __shared__ int cur[NB];
    for (int i = threadIdx.x; i < NB; i += 256) cur[i] = cstart[i * NG + blockIdx.x];
    __syncthreads();
    const int chunk = (E + NG - 1) / NG;
    const int lo = blockIdx.x * chunk, hi = min(E, lo + chunk);
    for (int e = lo + threadIdx.x; e < hi; e += 256) {
        int d = dst[e];
        int pos = atomicAdd(&cur[d >> 8], 1);
        staging[pos] = src[e] | ((d & 255) << 17);
    }
}

// ---------------- pass D: per-bucket CSR finalize + row_start + dis + x->fp16 (sliced) ----------------
__global__ __launch_bounds__(256) void bfinal_kernel(const int* __restrict__ cstart,
                                                     const int* __restrict__ staging,
                                                     int* __restrict__ csr_src,
                                                     int* __restrict__ row_start,
                                                     float* __restrict__ dis,
                                                     const float* __restrict__ x,
                                                     __half* __restrict__ xh,
                                                     int N, int E) {
    __shared__ int h[256];
    __shared__ int sc[256];
    __shared__ int cur[256];
    __shared__ float sdis[256];
    const int b = blockIdx.x, t = threadIdx.x;
    const int base = cstart[b * NG];
    const int endb = (b == NB - 1) ? E : cstart[(b + 1) * NG];
    h[t] = 0; __syncthreads();
    for (int i = base + t; i < endb; i += 256) atomicAdd(&h[staging[i] >> 17], 1);
    __syncthreads();
    int v = h[t];
    sc[t] = v; __syncthreads();
    for (int off = 1; off < 256; off <<= 1) {
        int xv = (t >= off) ? sc[t - off] : 0; __syncthreads();
        sc[t] += xv; __syncthreads();
    }
    int excl = sc[t] - v;
    cur[t] = base + excl;
    float dv = rsqrtf((float)v + 1.0f);
    sdis[t] = dv;
    int node = b * 256 + t;
    if (node < N) {
        row_start[node] = base + excl;
        dis[node] = dv;
    }
    if (b == NB - 1 && t == 0) row_start[N] = E;
    __syncthreads();
    for (int i = base + t; i < endb; i += 256) {
        int p = staging[i];
        int pos = atomicAdd(&cur[p >> 17], 1);
        csr_src[pos] = p & 0x1FFFF;
    }
    // fused: xh2[slice][node][16] = dis[node] * x[node][slice*16..]  (fp16, sliced)
    const int node0 = b * 256;
    const int nmax = min(256, N - node0);
    for (int i = t; i < nmax * 16; i += 256) {
        int nl = i >> 4, c4 = i & 15;            // c4 = float4 chunk (4 cols)
        float4 vx = ((const float4*)x)[(size_t)(node0 + nl) * 16 + c4];
        float wq = sdis[nl];
        // cols c4*4..c4*4+3 live in slice c4>>2 at within-slice offset (c4&3)*4
        __half2* o = (__half2*)&xh[((size_t)(c4 >> 2) * NN + (node0 + nl)) * 16 + (c4 & 3) * 4];
        o[0] = __floats2half2_rn(vx.x * wq, vx.y * wq);
        o[1] = __floats2half2_rn(vx.z * wq, vx.w * wq);
    }
}

// ---------------- both weight transposes in one launch ----------------
__global__ void cvtW_kernel(const float* __restrict__ W1, const float* __restrict__ W2,
                            __half* __restrict__ W1t, __half* __restrict__ W2t) {
    int i = blockIdx.x * 256 + threadIdx.x;
    if (i < 64 * 128) {
        int k = i / 128, c = i % 128;
        W1t[c * 64 + k] = __float2half(W1[i]);
        int k2 = i / 64, c2 = i % 64;
        W2t[c2 * 128 + k2] = __float2half(W2[i]);
    }
}

// ---------------- MFMA GEMM: C = A @ Wt^T ----------------
// ASLICED: A is [K/16][N][16] sliced fp16 ; else row-major [N][K]
// EPI 0: C row-major fp16 = relu(acc + bias[col]); EPI 1: C sliced fp16 = acc*dis[row]
template<int K, int F, int EPI, bool ASLICED>
__global__ __launch_bounds__(256) void gemm_mfma_kernel(const __half* __restrict__ A,
                                                        const __half* __restrict__ Wt,
                                                        const float* __restrict__ bias,
                                                        const float* __restrict__ dis,
                                                        __half* __restrict__ C, int N) {
    constexpr int BM = 32;
    constexpr int NT = F / 32;
    const int wid  = threadIdx.x >> 6;
    const int lane = threadIdx.x & 63;
    const int wr = wid >> 1;
    const int wc = wid & 1;
    const int row0 = blockIdx.x * BM + wr * 16;
    const int col0 = wc * (F / 2);
    const int lrow = lane & 15;
    const int kgrp = lane >> 4;

    f32x4 acc[NT];
    #pragma unroll
    for (int nt = 0; nt < NT; ++nt) acc[nt] = (f32x4){0.f, 0.f, 0.f, 0.f};

    #pragma unroll
    for (int ks = 0; ks < K / 32; ++ks) {
        const int kbase = ks * 32 + kgrp * 8;
        f16x8 a;
        if (ASLICED)
            a = *reinterpret_cast<const f16x8*>(&A[((size_t)(kbase >> 4) * NN + row0 + lrow) * 16 + (kbase & 15)]);
        else
            a = *reinterpret_cast<const f16x8*>(&A[(size_t)(row0 + lrow) * K + kbase]);
        #pragma unroll
        for (int nt = 0; nt < NT; ++nt) {
            f16x8 b = *reinterpret_cast<const f16x8*>(&Wt[(size_t)(col0 + nt * 16 + lrow) * K + kbase]);
            acc[nt] = __builtin_amdgcn_mfma_f32_16x16x32_f16(a, b, acc[nt], 0, 0, 0);
        }
    }
    #pragma unroll
    for (int nt = 0; nt < NT; ++nt) {
        const int col = col0 + nt * 16 + lrow;
        float bb = (EPI == 0) ? bias[col] : 0.0f;
        #pragma unroll
        for (int r = 0; r < 4; ++r) {
            const int row = row0 + kgrp * 4 + r;
            float v = acc[nt][r];
            if (EPI == 0) {
                v = fmaxf(v + bb, 0.0f);
                C[(size_t)row * F + col] = __float2half(v);
            } else {
                v = v * dis[row];
                C[((size_t)(col >> 4) * NN + row) * 16 + (col & 15)] = __float2half(v);
            }
        }
    }
}

// ---------------- sliced gather: one 16-col slice per block, slice L2-resident per XCD ----------------
// tab2: [4][N][16] fp16. lane = q*16 + e*2 + h : q=node-in-quad, e=edge slot, h=col half.
// OUT_SLICED: out fp16 [4][N][16]; else out fp32 row-major [N][64] (+bias)
template<bool BIAS, bool OUT_SLICED>
__global__ __launch_bounds__(256) void gatherS_kernel(const __half* __restrict__ tab2,
                                                      const float* __restrict__ dis,
                                                      const float* __restrict__ b,
                                                      const int* __restrict__ row_start,
                                                      const int* __restrict__ csr_src,
                                                      void* __restrict__ out_, int N,
                                                      float one) {
    const int wgid  = blockIdx.x;
    const int slice = wgid & 3;              // XCD k (wgid%8) sees only slice k&3
    const int chunk = wgid >> 2;
    const int wv = threadIdx.x >> 6;
    const int lane = threadIdx.x & 63;
    const int q = lane >> 4;
    const int e = (lane >> 1) & 7;
    const int h = lane & 1;
    const int node = chunk * 16 + wv * 4 + q;    // N divisible by 16: no bounds check
    const __half* ts = tab2 + (size_t)slice * N * 16;
    const int beg = row_start[node], end = row_start[node + 1];

    float acc[8];
    {   // self loop counted once via slot 0 (both halves)
        f16x8 sv = *reinterpret_cast<const f16x8*>(&ts[(size_t)node * 16 + h * 8]);
        #pragma unroll
        for (int k = 0; k < 8; ++k) acc[k] = (e == 0) ? (float)sv[k] : 0.0f;
    }
    int j = beg;
    for (; j + 8 <= end; j += 8) {
        int s = csr_src[j + e];
        f16x8 v = *reinterpret_cast<const f16x8*>(&ts[(size_t)s * 16 + h * 8]);
        #pragma unroll
        for (int k = 0; k < 8; ++k) acc[k] = fmaf((float)v[k], one, acc[k]);
    }
    if (j + e < end) {
        int s = csr_src[j + e];
        f16x8 v = *reinterpret_cast<const f16x8*>(&ts[(size_t)s * 16 + h * 8]);
        #pragma unroll
        for (int k = 0; k < 8; ++k) acc[k] = fmaf((float)v[k], one, acc[k]);
    }
    // reduce over edge slots e (lane bits 1..3)
    #pragma unroll
    for (int k = 0; k < 8; ++k) {
        acc[k] += __shfl_xor(acc[k], 2);
        acc[k] += __shfl_xor(acc[k], 4);
        acc[k] += __shfl_xor(acc[k], 8);
    }
    if (e == 0) {
        const float dd = dis[node];
        if constexpr (OUT_SLICED) {
            __half* out = (__half*)out_;
            f16x8 o;
            #pragma unroll
            for (int k = 0; k < 8; ++k) o[k] = (_Float16)(acc[k] * dd);
            *reinterpret_cast<f16x8*>(&out[((size_t)slice * N + node) * 16 + h * 8]) = o;
        } else {
            float* out = (float*)out_;
            float vv[8];
            #pragma unroll
            for (int k = 0; k < 8; ++k) {
                float v = acc[k] * dd;
                if (BIAS) v += b[slice * 16 + h * 8 + k];
                vv[k] = v;
            }
            float* op = &out[(size_t)node * 64 + slice * 16 + h * 8];
            *reinterpret_cast<float4*>(op)     = make_float4(vv[0], vv[1], vv[2], vv[3]);
            *reinterpret_cast<float4*>(op + 4) = make_float4(vv[4], vv[5], vv[6], vv[7]);
        }
    }
}

extern "C" void kernel_launch(void* const* d_in, const int* in_sizes, int n_in,
                              void* d_out, int out_size, void* d_ws, size_t ws_size,
                              hipStream_t stream) {
    const float* x  = (const float*)d_in[0];
    const int*   ei = (const int*)d_in[1];
    const float* W1 = (const float*)d_in[2];
    const float* b1 = (const float*)d_in[3];
    const float* W2 = (const float*)d_in[4];
    const float* b2 = (const float*)d_in[5];
    float* out = (float*)d_out;

    const int N = NN;
    const int E = in_sizes[1] / 2;
    const int* src = ei;
    const int* dst = ei + E;
    const int M = NB * NG;
    const int scan_blocks = (M + SCAN_B - 1) / SCAN_B;

    // workspace layout (4-byte words)
    int* counts    = (int*)d_ws;                 // M
    int* blk_sums  = counts + M;                 // 1024
    int* blk_off   = blk_sums + 1024;            // 1024
    int* row_start = blk_off + 1024;             // N+1 (+pad)
    float* dis     = (float*)(row_start + N + 64);
    int* staging   = (int*)(dis + N);            // E
    int* csr_src   = staging + E;                // E
    float* base    = (float*)(csr_src + E);
    __half* xh2    = (__half*)base;                       // [4][N][16] = N*64 halves
    __half* aggh2  = (__half*)(base + (size_t)N * 32);    // [4][N][16]
    __half* zh2    = (__half*)(base + (size_t)N * 64);    // [4][N][16]
    __half* h1h    = (__half*)(base + (size_t)N * 96);    // N*128 row-major
    __half* W1t    = (__half*)(base + (size_t)N * 160);   // 8192
    __half* W2t    = W1t + 128 * 64;                      // 8192

    // ---- CSR build (R8 structure: bucketed, global-scan) + fused sliced x-cvt ----
    bhist_kernel<<<NG, 256, 0, stream>>>(dst, counts, E);
    scan1_kernel<<<scan_blocks, SCAN_B, 0, stream>>>(counts, blk_sums, M);
    scan2_kernel<<<1, SCAN_B, 0, stream>>>(blk_sums, blk_off, scan_blocks);
    scan3_kernel<<<scan_blocks, SCAN_B, 0, stream>>>(counts, blk_off, M);
    bscatter_kernel<<<NG, 256, 0, stream>>>(src, dst, counts, staging, E);
    bfinal_kernel<<<NB, 256, 0, stream>>>(counts, staging, csr_src, row_start, dis, x, xh2, N, E);

    // ---- weights ----
    cvtW_kernel<<<(64 * 128 + 255) / 256, 256, 0, stream>>>(W1, W2, W1t, W2t);

    const int gblocks = (N / 16) * 4;   // 25000

    // ---- layer 1: aggh2 = A_hat-gather(xh2) (sliced), h1h = relu(aggh2@W1+b1) ----
    gatherS_kernel<false, true><<<gblocks, 256, 0, stream>>>(xh2, dis, nullptr, row_start, csr_src, aggh2, N, 1.0f);
    gemm_mfma_kernel<64, 128, 0, true><<<N / 32, 256, 0, stream>>>(aggh2, W1t, b1, nullptr, h1h, N);

    // ---- layer 2: zh2 = (h1h@W2)*dis (sliced), out = A_hat-gather(zh2) + b2 ----
    gemm_mfma_kernel<128, 64, 1, false><<<N / 32, 256, 0, stream>>>(h1h, W2t, nullptr, dis, zh2, N);
    gatherS_kernel<true, false><<<gblocks, 256, 0, stream>>>(zh2, dis, b2, row_start, csr_src, out, N, 1.0f);
}

// Round 11
// 182.063 us; speedup vs baseline: 1.1243x; 1.1243x over previous
//
#include <hip/hip_runtime.h>
#include <hip/hip_fp16.h>

#define NN 100000
#define NB 391        // ceil(NN/256) buckets of 256 dst nodes
#define NG 256        // edge-pass blocks
#define REGION 6144   // padded per-bucket staging/csr region (mean 4096, +32 sigma)

using f16x8 = __attribute__((ext_vector_type(8))) _Float16;
using f32x4 = __attribute__((ext_vector_type(4))) float;

// ---------------- pass A: per-block bucket histogram (LDS) ----------------
__global__ __launch_bounds__(256) void bhist_kernel(const int* __restrict__ dst,
                                                    int* __restrict__ counts, int E) {
    __shared__ int h[NB];
    for (int i = threadIdx.x; i < NB; i += 256) h[i] = 0;
    __syncthreads();
    const int chunk = (E + NG - 1) / NG;
    const int lo = blockIdx.x * chunk, hi = min(E, lo + chunk);
    for (int e = lo + threadIdx.x; e < hi; e += 256) atomicAdd(&h[dst[e] >> 8], 1);
    __syncthreads();
    for (int i = threadIdx.x; i < NB; i += 256) counts[i * NG + blockIdx.x] = h[i];
}

// ---------------- pass B: per-bucket prefix (padded regions) + folded cvtW ----------------
__global__ __launch_bounds__(256) void bprefix_kernel(int* __restrict__ counts,
                                                      int* __restrict__ btot,
                                                      const float* __restrict__ W1,
                                                      const float* __restrict__ W2,
                                                      __half* __restrict__ W1t,
                                                      __half* __restrict__ W2t) {
    const int b = blockIdx.x, t = threadIdx.x;
    if (b == NB) {   // weight transposes, one extra block
        for (int i = t; i < 64 * 128; i += 256) {
            int k = i / 128, c = i % 128;
            W1t[c * 64 + k] = __float2half(W1[i]);
            int k2 = i / 64, c2 = i % 64;
            W2t[c2 * 128 + k2] = __float2half(W2[i]);
        }
        return;
    }
    __shared__ int sm[256];
    int v = counts[b * NG + t];
    sm[t] = v; __syncthreads();
    for (int off = 1; off < 256; off <<= 1) {
        int x = (t >= off) ? sm[t - off] : 0; __syncthreads();
        sm[t] += x; __syncthreads();
    }
    counts[b * NG + t] = b * REGION + sm[t] - v;   // exclusive, region-based
    if (t == 255) btot[b] = sm[255];
}

// ---------------- pass C: scatter edges into bucket-region staging ----------------
__global__ __launch_bounds__(256) void bscatter_kernel(const int* __restrict__ src,
                                                       const int* __restrict__ dst,
                                                       const int* __restrict__ cstart,
                                                       int* __restrict__ staging, int E) {
    __shared__ int cur[NB];
    for (int i = threadIdx.x; i < NB; i += 256) cur[i] = cstart[i * NG + blockIdx.x];
    __syncthreads();
    const int chunk = (E + NG - 1) / NG;
    const int lo = blockIdx.x * chunk, hi = min(E, lo + chunk);
    for (int e = lo + threadIdx.x; e < hi; e += 256) {
        int d = dst[e];
        int pos = atomicAdd(&cur[d >> 8], 1);
        staging[pos] = src[e] | ((d & 255) << 17);
    }
}

// ---------------- pass D: per-bucket CSR finalize + row_beg/end + dis + x->fp16 ----------------
__global__ __launch_bounds__(256) void bfinal_kernel(const int* __restrict__ btot,
                                                     const int* __restrict__ staging,
                                                     int* __restrict__ csr,
                                                     int* __restrict__ row_beg,
                                                     int* __restrict__ row_end,
                                                     float* __restrict__ dis,
                                                     const float* __restrict__ x,
                                                     __half* __restrict__ xh,
                                                     int N) {
    __shared__ int h[256];
    __shared__ int sc[256];
    __shared__ int cur[256];
    __shared__ float sdis[256];
    const int b = blockIdx.x, t = threadIdx.x;
    const int base = b * REGION;
    const int endb = base + btot[b];
    h[t] = 0; __syncthreads();
    for (int i = base + t; i < endb; i += 256) atomicAdd(&h[staging[i] >> 17], 1);
    __syncthreads();
    int v = h[t];
    sc[t] = v; __syncthreads();
    for (int off = 1; off < 256; off <<= 1) {
        int xv = (t >= off) ? sc[t - off] : 0; __syncthreads();
        sc[t] += xv; __syncthreads();
    }
    int excl = sc[t] - v;
    cur[t] = base + excl;
    float dv = rsqrtf((float)v + 1.0f);
    sdis[t] = dv;
    int node = b * 256 + t;
    if (node < N) {
        row_beg[node] = base + excl;
        row_end[node] = base + excl + v;
        dis[node] = dv;
    }
    __syncthreads();
    for (int i = base + t; i < endb; i += 256) {
        int p = staging[i];
        int pos = atomicAdd(&cur[p >> 17], 1);
        csr[pos] = p & 0x1FFFF;
    }
    // fused: xh[node] = dis[node]*x[node] (fp16, row-major)
    const int node0 = b * 256;
    const int nmax = min(256, N - node0);
    for (int i = t; i < nmax * 16; i += 256) {
        int nl = i >> 4, c4 = i & 15;
        float4 vx = ((const float4*)x)[(size_t)(node0 + nl) * 16 + c4];
        float wq = sdis[nl];
        __half2* o = (__half2*)&xh[(size_t)(node0 + nl) * 64 + c4 * 4];
        o[0] = __floats2half2_rn(vx.x * wq, vx.y * wq);
        o[1] = __floats2half2_rn(vx.z * wq, vx.w * wq);
    }
}

// ---------------- fused gather + GEMM1: h1h = relu((A_hat-gather(xh)) @ W1 + b1) ----------------
// 16 nodes/block; per node 16 lanes: e = edge slot (2), sub = col octet (8x16B = full row).
__global__ __launch_bounds__(256) void gatherG1_kernel(const __half* __restrict__ tab,
                                                       const float* __restrict__ dis,
                                                       const __half* __restrict__ W1t,
                                                       const float* __restrict__ b1,
                                                       const int* __restrict__ row_beg,
                                                       const int* __restrict__ row_end,
                                                       const int* __restrict__ csr,
                                                       __half* __restrict__ h1h, int N,
                                                       float one) {
    __shared__ _Float16 sA[16][72];   // 16x64 agg tile, padded
    const int tid = threadIdx.x;
    const int nodeL = tid >> 4;
    const int node = blockIdx.x * 16 + nodeL;
    const int l16 = tid & 15;
    const int e = l16 >> 3;
    const int sub = l16 & 7;
    const int beg = row_beg[node], end = row_end[node];

    float acc[8];
    if (e == 0) {   // self loop (dis[s] folded in tab)
        f16x8 sv = *reinterpret_cast<const f16x8*>(&tab[(size_t)node * 64 + sub * 8]);
        #pragma unroll
        for (int q = 0; q < 8; ++q) acc[q] = (float)sv[q];
    } else {
        #pragma unroll
        for (int q = 0; q < 8; ++q) acc[q] = 0.0f;
    }
    for (int j = beg + e; j < end; j += 2) {
        int s = csr[j];
        f16x8 v = *reinterpret_cast<const f16x8*>(&tab[(size_t)s * 64 + sub * 8]);
        #pragma unroll
        for (int q = 0; q < 8; ++q) acc[q] = fmaf((float)v[q], one, acc[q]);
    }
    #pragma unroll
    for (int q = 0; q < 8; ++q) acc[q] += __shfl_xor(acc[q], 8);

    if (e == 0) {
        const float dd = dis[node];
        f16x8 o;
        #pragma unroll
        for (int q = 0; q < 8; ++q) o[q] = (_Float16)(acc[q] * dd);
        *reinterpret_cast<f16x8*>(&sA[nodeL][sub * 8]) = o;
    }
    __syncthreads();

    // MFMA phase: 4 waves x 2 col-tiles, K=64
    const int wid = tid >> 6, lane = tid & 63;
    const int lrow = lane & 15, kgrp = lane >> 4;
    f32x4 acc2[2];
    acc2[0] = (f32x4){0.f, 0.f, 0.f, 0.f};
    acc2[1] = (f32x4){0.f, 0.f, 0.f, 0.f};
    #pragma unroll
    for (int ks = 0; ks < 2; ++ks) {
        const int kbase = ks * 32 + kgrp * 8;
        f16x8 a = *reinterpret_cast<const f16x8*>(&sA[lrow][kbase]);
        #pragma unroll
        for (int nt = 0; nt < 2; ++nt) {
            const int col = (wid * 2 + nt) * 16 + lrow;
            f16x8 b = *reinterpret_cast<const f16x8*>(&W1t[(size_t)col * 64 + kbase]);
            acc2[nt] = __builtin_amdgcn_mfma_f32_16x16x32_f16(a, b, acc2[nt], 0, 0, 0);
        }
    }
    #pragma unroll
    for (int nt = 0; nt < 2; ++nt) {
        const int col = (wid * 2 + nt) * 16 + lrow;
        const float bb = b1[col];
        #pragma unroll
        for (int r = 0; r < 4; ++r) {
            const int row = blockIdx.x * 16 + kgrp * 4 + r;
            float v = fmaxf(acc2[nt][r] + bb, 0.0f);
            h1h[(size_t)row * 128 + col] = __float2half(v);
        }
    }
}

// ---------------- MFMA GEMM2: zh[N,64](fp16) = h1h[N,128] @ W2t^T, epilogue *dis ----------------
__global__ __launch_bounds__(256) void gemm2_kernel(const __half* __restrict__ A,
                                                    const __half* __restrict__ Wt,
                                                    const float* __restrict__ dis,
                                                    __half* __restrict__ C, int N) {
    constexpr int K = 128, F = 64;
    constexpr int NT = F / 32;
    const int wid  = threadIdx.x >> 6;
    const int lane = threadIdx.x & 63;
    const int wr = wid >> 1;
    const int wc = wid & 1;
    const int row0 = blockIdx.x * 32 + wr * 16;
    const int col0 = wc * (F / 2);
    const int lrow = lane & 15;
    const int kgrp = lane >> 4;

    f32x4 acc[NT];
    #pragma unroll
    for (int nt = 0; nt < NT; ++nt) acc[nt] = (f32x4){0.f, 0.f, 0.f, 0.f};
    #pragma unroll
    for (int ks = 0; ks < K / 32; ++ks) {
        const int kbase = ks * 32 + kgrp * 8;
        f16x8 a = *reinterpret_cast<const f16x8*>(&A[(size_t)(row0 + lrow) * K + kbase]);
        #pragma unroll
        for (int nt = 0; nt < NT; ++nt) {
            f16x8 b = *reinterpret_cast<const f16x8*>(&Wt[(size_t)(col0 + nt * 16 + lrow) * K + kbase]);
            acc[nt] = __builtin_amdgcn_mfma_f32_16x16x32_f16(a, b, acc[nt], 0, 0, 0);
        }
    }
    #pragma unroll
    for (int nt = 0; nt < NT; ++nt) {
        const int col = col0 + nt * 16 + lrow;
        #pragma unroll
        for (int r = 0; r < 4; ++r) {
            const int row = row0 + kgrp * 4 + r;
            C[(size_t)row * F + col] = __float2half(acc[nt][r] * dis[row]);
        }
    }
}

// ---------------- gather2: 1 wave/node, 16 edges/iter, out fp32 + bias ----------------
__global__ __launch_bounds__(256) void gather2_kernel(const __half* __restrict__ tab,
                                                      const float* __restrict__ dis,
                                                      const float* __restrict__ b,
                                                      const int* __restrict__ row_beg,
                                                      const int* __restrict__ row_end,
                                                      const int* __restrict__ csr,
                                                      float* __restrict__ out, int N,
                                                      float one) {
    const int node = blockIdx.x * 4 + (threadIdx.x >> 6);
    const int lane = threadIdx.x & 63;
    const int g   = lane >> 3;
    const int sub = lane & 7;
    if (node >= N) return;
    const int beg = row_beg[node], end = row_end[node];

    float acc[8];
    {   // self loop via slot 0
        f16x8 sv = *reinterpret_cast<const f16x8*>(&tab[(size_t)node * 64 + sub * 8]);
        #pragma unroll
        for (int q = 0; q < 8; ++q) acc[q] = (g == 0) ? (float)sv[q] : 0.0f;
    }
    int j = beg;
    for (; j + 16 <= end; j += 16) {
        int sA = csr[j + g];
        int sB = csr[j + 8 + g];
        f16x8 vA = *reinterpret_cast<const f16x8*>(&tab[(size_t)sA * 64 + sub * 8]);
        f16x8 vB = *reinterpret_cast<const f16x8*>(&tab[(size_t)sB * 64 + sub * 8]);
        #pragma unroll
        for (int q = 0; q < 8; ++q) acc[q] = fmaf((float)vA[q], one, acc[q]);
        #pragma unroll
        for (int q = 0; q < 8; ++q) acc[q] = fmaf((float)vB[q], one, acc[q]);
    }
    if (j + 8 <= end) {
        int s = csr[j + g];
        f16x8 v = *reinterpret_cast<const f16x8*>(&tab[(size_t)s * 64 + sub * 8]);
        #pragma unroll
        for (int q = 0; q < 8; ++q) acc[q] = fmaf((float)v[q], one, acc[q]);
        j += 8;
    }
    if (j + g < end) {
        int s = csr[j + g];
        f16x8 v = *reinterpret_cast<const f16x8*>(&tab[(size_t)s * 64 + sub * 8]);
        #pragma unroll
        for (int q = 0; q < 8; ++q) acc[q] = fmaf((float)v[q], one, acc[q]);
    }
    #pragma unroll
    for (int q = 0; q < 8; ++q) {
        acc[q] += __shfl_xor(acc[q], 8);
        acc[q] += __shfl_xor(acc[q], 16);
        acc[q] += __shfl_xor(acc[q], 32);
    }
    if (g == 0) {
        const float dd = dis[node];
        float vv[8];
        #pragma unroll
        for (int q = 0; q < 8; ++q) vv[q] = acc[q] * dd + b[sub * 8 + q];
        float* op = &out[(size_t)node * 64 + sub * 8];
        *reinterpret_cast<float4*>(op)     = make_float4(vv[0], vv[1], vv[2], vv[3]);
        *reinterpret_cast<float4*>(op + 4) = make_float4(vv[4], vv[5], vv[6], vv[7]);
    }
}

extern "C" void kernel_launch(void* const* d_in, const int* in_sizes, int n_in,
                              void* d_out, int out_size, void* d_ws, size_t ws_size,
                              hipStream_t stream) {
    const float* x  = (const float*)d_in[0];
    const int*   ei = (const int*)d_in[1];
    const float* W1 = (const float*)d_in[2];
    const float* b1 = (const float*)d_in[3];
    const float* W2 = (const float*)d_in[4];
    const float* b2 = (const float*)d_in[5];
    float* out = (float*)d_out;

    const int N = NN;
    const int E = in_sizes[1] / 2;
    const int* src = ei;
    const int* dst = ei + E;

    // workspace layout (4-byte words)
    int* counts   = (int*)d_ws;                       // NB*NG
    int* btot     = counts + NB * NG;                 // NB (+pad)
    int* row_beg  = btot + 512;                       // N
    int* row_end  = row_beg + N;                      // N
    float* dis    = (float*)(row_end + N);            // N
    int* staging  = (int*)(dis + N);                  // NB*REGION
    int* csr      = staging + (size_t)NB * REGION;    // NB*REGION
    float* base   = (float*)(csr + (size_t)NB * REGION);
    __half* xh    = (__half*)base;                        // N*64 halves
    __half* zh    = (__half*)(base + (size_t)N * 32);     // N*64
    __half* h1h   = (__half*)(base + (size_t)N * 64);     // N*128
    __half* W1t   = (__half*)(base + (size_t)N * 128);    // 8192
    __half* W2t   = W1t + 128 * 64;                       // 8192

    // ---- CSR build (4 kernels) ----
    bhist_kernel<<<NG, 256, 0, stream>>>(dst, counts, E);
    bprefix_kernel<<<NB + 1, 256, 0, stream>>>(counts, btot, W1, W2, W1t, W2t);
    bscatter_kernel<<<NG, 256, 0, stream>>>(src, dst, counts, staging, E);
    bfinal_kernel<<<NB, 256, 0, stream>>>(btot, staging, csr, row_beg, row_end, dis, x, xh, N);

    // ---- layer 1 fused: h1h = relu(gather(xh)@W1 + b1) ----
    gatherG1_kernel<<<N / 16, 256, 0, stream>>>(xh, dis, W1t, b1, row_beg, row_end, csr, h1h, N, 1.0f);

    // ---- layer 2: zh = (h1h@W2)*dis, out = gather(zh) + b2 ----
    gemm2_kernel<<<N / 32, 256, 0, stream>>>(h1h, W2t, dis, zh, N);
    gather2_kernel<<<N / 4, 256, 0, stream>>>(zh, dis, b2, row_beg, row_end, csr, out, N, 1.0f);
}

// Round 12
// 166.343 us; speedup vs baseline: 1.2305x; 1.0945x over previous
//
#include <hip/hip_runtime.h>
#include <hip/hip_fp16.h>

#define NN 100000
#define NB 391        // ceil(NN/256) buckets of 256 dst nodes
#define NG 512        // edge-pass blocks
#define REGION 6144   // padded per-bucket staging/csr region (mean 4096, +32 sigma)

using f16x8 = __attribute__((ext_vector_type(8))) _Float16;
using f32x4 = __attribute__((ext_vector_type(4))) float;

// ---------------- pass A: per-block bucket histogram (LDS), counts[NG][NB] ----------------
__global__ __launch_bounds__(256) void bhist_kernel(const int* __restrict__ dst,
                                                    int* __restrict__ counts, int E) {
    __shared__ int h[NB];
    for (int i = threadIdx.x; i < NB; i += 256) h[i] = 0;
    __syncthreads();
    const int g = blockIdx.x;
    const int chunk = (E + NG - 1) / NG;
    const int lo = g * chunk, hi = min(E, lo + chunk);
    for (int e = lo + threadIdx.x; e < hi; e += 256) atomicAdd(&h[dst[e] >> 8], 1);
    __syncthreads();
    for (int i = threadIdx.x; i < NB; i += 256) counts[g * NB + i] = h[i];
}

// ---------------- pass B: per-bucket prefix over NG entries (padded regions) + folded cvtW ----------------
__global__ __launch_bounds__(256) void bprefix_kernel(int* __restrict__ counts,
                                                      int* __restrict__ btot,
                                                      const float* __restrict__ W1,
                                                      const float* __restrict__ W2,
                                                      __half* __restrict__ W1t,
                                                      __half* __restrict__ W2t) {
    const int b = blockIdx.x, t = threadIdx.x;
    if (b == NB) {   // weight transposes, one extra block
        for (int i = t; i < 64 * 128; i += 256) {
            int k = i / 128, c = i % 128;
            W1t[c * 64 + k] = __float2half(W1[i]);
            int k2 = i / 64, c2 = i % 64;
            W2t[c2 * 128 + k2] = __float2half(W2[i]);
        }
        return;
    }
    __shared__ int sm[256];
    int loc[NG / 256];
    int s = 0;
    #pragma unroll
    for (int p = 0; p < NG / 256; ++p) {
        loc[p] = counts[((NG / 256) * t + p) * NB + b];
        s += loc[p];
    }
    sm[t] = s; __syncthreads();
    for (int off = 1; off < 256; off <<= 1) {
        int x = (t >= off) ? sm[t - off] : 0; __syncthreads();
        sm[t] += x; __syncthreads();
    }
    int run = b * REGION + sm[t] - s;
    #pragma unroll
    for (int p = 0; p < NG / 256; ++p) {
        int c = loc[p];
        counts[((NG / 256) * t + p) * NB + b] = run;
        run += c;
    }
    if (t == 255) btot[b] = sm[255];
}

// ---------------- pass C: scatter edges into bucket-region staging ----------------
__global__ __launch_bounds__(256) void bscatter_kernel(const int* __restrict__ src,
                                                       const int* __restrict__ dst,
                                                       const int* __restrict__ cstart,
                                                       int* __restrict__ staging, int E) {
    __shared__ int cur[NB];
    const int g = blockIdx.x;
    for (int i = threadIdx.x; i < NB; i += 256) cur[i] = cstart[g * NB + i];
    __syncthreads();
    const int chunk = (E + NG - 1) / NG;
    const int lo = g * chunk, hi = min(E, lo + chunk);
    for (int e = lo + threadIdx.x; e < hi; e += 256) {
        int d = dst[e];
        int pos = atomicAdd(&cur[d >> 8], 1);
        staging[pos] = src[e] | ((d & 255) << 17);
    }
}

// ---------------- pass D: per-bucket CSR finalize + row_beg/end + dis + x->fp16 ----------------
__global__ __launch_bounds__(256) void bfinal_kernel(const int* __restrict__ btot,
                                                     const int* __restrict__ staging,
                                                     int* __restrict__ csr,
                                                     int* __restrict__ row_beg,
                                                     int* __restrict__ row_end,
                                                     float* __restrict__ dis,
                                                     const float* __restrict__ x,
                                                     __half* __restrict__ xh,
                                                     int N) {
    __shared__ int h[256];
    __shared__ int sc[256];
    __shared__ int cur[256];
    __shared__ float sdis[256];
    const int b = blockIdx.x, t = threadIdx.x;
    const int base = b * REGION;
    const int endb = base + btot[b];
    h[t] = 0; __syncthreads();
    for (int i = base + t; i < endb; i += 256) atomicAdd(&h[staging[i] >> 17], 1);
    __syncthreads();
    int v = h[t];
    sc[t] = v; __syncthreads();
    for (int off = 1; off < 256; off <<= 1) {
        int xv = (t >= off) ? sc[t - off] : 0; __syncthreads();
        sc[t] += xv; __syncthreads();
    }
    int excl = sc[t] - v;
    cur[t] = base + excl;
    float dv = rsqrtf((float)v + 1.0f);
    sdis[t] = dv;
    int node = b * 256 + t;
    if (node < N) {
        row_beg[node] = base + excl;
        row_end[node] = base + excl + v;
        dis[node] = dv;
    }
    __syncthreads();
    for (int i = base + t; i < endb; i += 256) {
        int p = staging[i];
        int pos = atomicAdd(&cur[p >> 17], 1);
        csr[pos] = p & 0x1FFFF;
    }
    // fused: xh[node] = dis[node]*x[node] (fp16, row-major)
    const int node0 = b * 256;
    const int nmax = min(256, N - node0);
    for (int i = t; i < nmax * 16; i += 256) {
        int nl = i >> 4, c4 = i & 15;
        float4 vx = ((const float4*)x)[(size_t)(node0 + nl) * 16 + c4];
        float wq = sdis[nl];
        __half2* o = (__half2*)&xh[(size_t)(node0 + nl) * 64 + c4 * 4];
        o[0] = __floats2half2_rn(vx.x * wq, vx.y * wq);
        o[1] = __floats2half2_rn(vx.z * wq, vx.w * wq);
    }
}

// ---------------- fused layer1+layer2-GEMM: zh = (relu(gather(xh)@W1+b1) @ W2) * dis ----------------
// 512 threads, 16 nodes/block. Gather: 32 lanes/node (4 edge slots x 8 col-octets).
// Then gemm1 (8 waves x 16 of 128 cols, K=64) -> sH; gemm2 split-K (wave pairs, K=128) -> zh.
__global__ __launch_bounds__(512) void gfuse_kernel(const __half* __restrict__ tab,
                                                    const float* __restrict__ dis,
                                                    const __half* __restrict__ W1t,
                                                    const float* __restrict__ b1,
                                                    const __half* __restrict__ W2t,
                                                    const int* __restrict__ row_beg,
                                                    const int* __restrict__ row_end,
                                                    const int* __restrict__ csr,
                                                    __half* __restrict__ zh, int N,
                                                    float one) {
    __shared__ _Float16 sA[16][72];    // 16x64 agg tile (dis-scaled), padded
    __shared__ _Float16 sH[16][136];   // 16x128 h1 tile, padded
    __shared__ float sP[4][16][16];    // gemm2 K-half partials
    const int tid = threadIdx.x;
    const int nodeL = tid >> 5;
    const int l32 = tid & 31;
    const int e = l32 >> 3;           // edge slot 0..3
    const int sub = l32 & 7;          // col octet
    const int node0 = blockIdx.x * 16;
    const int node = node0 + nodeL;
    const int beg = row_beg[node], end = row_end[node];

    float acc[8];
    {   // self loop counted once via slot 0 (dis[s] folded in tab)
        f16x8 sv = *reinterpret_cast<const f16x8*>(&tab[(size_t)node * 64 + sub * 8]);
        #pragma unroll
        for (int q = 0; q < 8; ++q) acc[q] = (e == 0) ? (float)sv[q] : 0.0f;
    }
    for (int j = beg + e; j < end; j += 4) {
        int s = csr[j];
        f16x8 v = *reinterpret_cast<const f16x8*>(&tab[(size_t)s * 64 + sub * 8]);
        #pragma unroll
        for (int q = 0; q < 8; ++q) acc[q] = fmaf((float)v[q], one, acc[q]);
    }
    #pragma unroll
    for (int q = 0; q < 8; ++q) {
        acc[q] += __shfl_xor(acc[q], 8);
        acc[q] += __shfl_xor(acc[q], 16);
    }
    if (e == 0) {
        const float dd = dis[node];
        f16x8 o;
        #pragma unroll
        for (int q = 0; q < 8; ++q) o[q] = (_Float16)(acc[q] * dd);
        *reinterpret_cast<f16x8*>(&sA[nodeL][sub * 8]) = o;
    }
    __syncthreads();

    const int w = tid >> 6, lane = tid & 63;
    const int lrow = lane & 15, kgrp = lane >> 4;
    // ---- gemm1: h1 = relu(sA @ W1 + b1), 8 waves x 16 cols, K=64 ----
    {
        const int col = w * 16 + lrow;
        f32x4 a1 = (f32x4){0.f, 0.f, 0.f, 0.f};
        #pragma unroll
        for (int ks = 0; ks < 2; ++ks) {
            const int kbase = ks * 32 + kgrp * 8;
            f16x8 a  = *reinterpret_cast<const f16x8*>(&sA[lrow][kbase]);
            f16x8 bf = *reinterpret_cast<const f16x8*>(&W1t[(size_t)col * 64 + kbase]);
            a1 = __builtin_amdgcn_mfma_f32_16x16x32_f16(a, bf, a1, 0, 0, 0);
        }
        const float bb = b1[col];
        #pragma unroll
        for (int r = 0; r < 4; ++r) {
            const int row = kgrp * 4 + r;
            sH[row][col] = (_Float16)fmaxf(a1[r] + bb, 0.0f);
        }
    }
    __syncthreads();
    // ---- gemm2 split-K: zh = (sH @ W2) * dis, 4 col tiles x 2 K-halves ----
    {
        const int t2 = w & 3, kh = w >> 2;
        const int col = t2 * 16 + lrow;
        f32x4 a2 = (f32x4){0.f, 0.f, 0.f, 0.f};
        #pragma unroll
        for (int ks = 0; ks < 2; ++ks) {
            const int kbase = kh * 64 + ks * 32 + kgrp * 8;
            f16x8 a  = *reinterpret_cast<const f16x8*>(&sH[lrow][kbase]);
            f16x8 bf = *reinterpret_cast<const f16x8*>(&W2t[(size_t)col * 128 + kbase]);
            a2 = __builtin_amdgcn_mfma_f32_16x16x32_f16(a, bf, a2, 0, 0, 0);
        }
        if (kh == 1) {
            #pragma unroll
            for (int r = 0; r < 4; ++r) sP[t2][kgrp * 4 + r][lrow] = a2[r];
        }
        __syncthreads();
        if (kh == 0) {
            #pragma unroll
            for (int r = 0; r < 4; ++r) {
                const int row = kgrp * 4 + r;
                float v = (a2[r] + sP[t2][row][lrow]) * dis[node0 + row];
                zh[(size_t)(node0 + row) * 64 + col] = __float2half(v);
            }
        }
    }
}

// ---------------- gather2: 1 wave/node, 16 edges/iter, out fp32 + bias ----------------
__global__ __launch_bounds__(256) void gather2_kernel(const __half* __restrict__ tab,
                                                      const float* __restrict__ dis,
                                                      const float* __restrict__ b,
                                                      const int* __restrict__ row_beg,
                                                      const int* __restrict__ row_end,
                                                      const int* __restrict__ csr,
                                                      float* __restrict__ out, int N,
                                                      float one) {
    const int node = blockIdx.x * 4 + (threadIdx.x >> 6);
    const int lane = threadIdx.x & 63;
    const int g   = lane >> 3;
    const int sub = lane & 7;
    if (node >= N) return;
    const int beg = row_beg[node], end = row_end[node];

    float acc[8];
    {   // self loop via slot 0
        f16x8 sv = *reinterpret_cast<const f16x8*>(&tab[(size_t)node * 64 + sub * 8]);
        #pragma unroll
        for (int q = 0; q < 8; ++q) acc[q] = (g == 0) ? (float)sv[q] : 0.0f;
    }
    int j = beg;
    for (; j + 16 <= end; j += 16) {
        int sA = csr[j + g];
        int sB = csr[j + 8 + g];
        f16x8 vA = *reinterpret_cast<const f16x8*>(&tab[(size_t)sA * 64 + sub * 8]);
        f16x8 vB = *reinterpret_cast<const f16x8*>(&tab[(size_t)sB * 64 + sub * 8]);
        #pragma unroll
        for (int q = 0; q < 8; ++q) acc[q] = fmaf((float)vA[q], one, acc[q]);
        #pragma unroll
        for (int q = 0; q < 8; ++q) acc[q] = fmaf((float)vB[q], one, acc[q]);
    }
    if (j + 8 <= end) {
        int s = csr[j + g];
        f16x8 v = *reinterpret_cast<const f16x8*>(&tab[(size_t)s * 64 + sub * 8]);
        #pragma unroll
        for (int q = 0; q < 8; ++q) acc[q] = fmaf((float)v[q], one, acc[q]);
        j += 8;
    }
    if (j + g < end) {
        int s = csr[j + g];
        f16x8 v = *reinterpret_cast<const f16x8*>(&tab[(size_t)s * 64 + sub * 8]);
        #pragma unroll
        for (int q = 0; q < 8; ++q) acc[q] = fmaf((float)v[q], one, acc[q]);
    }
    #pragma unroll
    for (int q = 0; q < 8; ++q) {
        acc[q] += __shfl_xor(acc[q], 8);
        acc[q] += __shfl_xor(acc[q], 16);
        acc[q] += __shfl_xor(acc[q], 32);
    }
    if (g == 0) {
        const float dd = dis[node];
        float vv[8];
        #pragma unroll
        for (int q = 0; q < 8; ++q) vv[q] = acc[q] * dd + b[sub * 8 + q];
        float* op = &out[(size_t)node * 64 + sub * 8];
        *reinterpret_cast<float4*>(op)     = make_float4(vv[0], vv[1], vv[2], vv[3]);
        *reinterpret_cast<float4*>(op + 4) = make_float4(vv[4], vv[5], vv[6], vv[7]);
    }
}

extern "C" void kernel_launch(void* const* d_in, const int* in_sizes, int n_in,
                              void* d_out, int out_size, void* d_ws, size_t ws_size,
                              hipStream_t stream) {
    const float* x  = (const float*)d_in[0];
    const int*   ei = (const int*)d_in[1];
    const float* W1 = (const float*)d_in[2];
    const float* b1 = (const float*)d_in[3];
    const float* W2 = (const float*)d_in[4];
    const float* b2 = (const float*)d_in[5];
    float* out = (float*)d_out;

    const int N = NN;
    const int E = in_sizes[1] / 2;
    const int* src = ei;
    const int* dst = ei + E;

    // workspace layout (4-byte words)
    int* counts   = (int*)d_ws;                       // NG*NB
    int* btot     = counts + NG * NB;                 // NB (+pad)
    int* row_beg  = btot + 512;                       // N
    int* row_end  = row_beg + N;                      // N
    float* dis    = (float*)(row_end + N);            // N
    int* staging  = (int*)(dis + N);                  // NB*REGION
    int* csr      = staging + (size_t)NB * REGION;    // NB*REGION
    float* base   = (float*)(csr + (size_t)NB * REGION);
    __half* xh    = (__half*)base;                        // N*64 halves
    __half* zh    = (__half*)(base + (size_t)N * 32);     // N*64 halves
    __half* W1t   = (__half*)(base + (size_t)N * 64);     // 8192 halves
    __half* W2t   = W1t + 128 * 64;                       // 8192 halves

    // ---- CSR build ----
    bhist_kernel<<<NG, 256, 0, stream>>>(dst, counts, E);
    bprefix_kernel<<<NB + 1, 256, 0, stream>>>(counts, btot, W1, W2, W1t, W2t);
    bscatter_kernel<<<NG, 256, 0, stream>>>(src, dst, counts, staging, E);
    bfinal_kernel<<<NB, 256, 0, stream>>>(btot, staging, csr, row_beg, row_end, dis, x, xh, N);

    // ---- fused layer1 + layer2-GEMM: zh = (relu(gather(xh)@W1+b1)@W2)*dis ----
    gfuse_kernel<<<N / 16, 512, 0, stream>>>(xh, dis, W1t, b1, W2t, row_beg, row_end, csr, zh, N, 1.0f);

    // ---- final gather: out = gather(zh) + b2 ----
    gather2_kernel<<<N / 4, 256, 0, stream>>>(zh, dis, b2, row_beg, row_end, csr, out, N, 1.0f);
}